// Round 14
// baseline (1038.398 us; speedup 1.0000x reference)
//
#include <hip/hip_runtime.h>
#include <stdint.h>

#define B_DIM 16384
#define V_DIM 1024
#define H_DIM 256
#define K_STEPS 8
#define HALF_B 8192

typedef short bf16x8 __attribute__((ext_vector_type(8)));
typedef float f32x4 __attribute__((ext_vector_type(4)));

// ---------------- Threefry-2x32-20, bit-exact JAX replica ----------------
__host__ __device__ inline uint32_t rotl32(uint32_t v, int r) {
#if defined(__HIP_DEVICE_COMPILE__)
    return __builtin_amdgcn_alignbit(v, v, (uint32_t)(32 - r));
#else
    return (v << r) | (v >> (32 - r));
#endif
}

__host__ __device__ inline void threefry2x32(uint32_t k0, uint32_t k1,
                                             uint32_t x0, uint32_t x1,
                                             uint32_t* o0, uint32_t* o1) {
    uint32_t k2 = k0 ^ k1 ^ 0x1BD11BDAu;
    x0 += k0; x1 += k1;
#define TF_RND(r) { x0 += x1; x1 = rotl32(x1, (r)); x1 ^= x0; }
    TF_RND(13) TF_RND(15) TF_RND(26) TF_RND(6)
    x0 += k1; x1 += k2 + 1u;
    TF_RND(17) TF_RND(29) TF_RND(16) TF_RND(24)
    x0 += k2; x1 += k0 + 2u;
    TF_RND(13) TF_RND(15) TF_RND(26) TF_RND(6)
    x0 += k0; x1 += k1 + 3u;
    TF_RND(17) TF_RND(29) TF_RND(16) TF_RND(24)
    x0 += k1; x1 += k2 + 4u;
    TF_RND(13) TF_RND(15) TF_RND(26) TF_RND(6)
    x0 += k2; x1 += k0 + 5u;
#undef TF_RND
    *o0 = x0; *o1 = x1;
}

// Partitionable-threefry uniform (bits = o0 ^ o1 of counter (0, e)).
__device__ inline float tf_uniform(uint32_t key0, uint32_t key1, uint32_t e) {
    uint32_t o0, o1;
    threefry2x32(key0, key1, 0u, e, &o0, &o1);
    uint32_t bits = o0 ^ o1;
    return __uint_as_float((bits >> 9) | 0x3f800000u) - 1.0f;
}

__device__ inline uint16_t bf16_rn(float f) {
    uint32_t u = __float_as_uint(f);
    uint32_t r = u + 0x7FFFu + ((u >> 16) & 1u);
    return (uint16_t)(r >> 16);
}
__device__ inline float bf16_to_f32(uint16_t h) {
    return __uint_as_float(((uint32_t)h) << 16);
}

__device__ inline void gload_lds16(const void* g, void* l) {
    __builtin_amdgcn_global_load_lds((const __attribute__((address_space(1))) uint32_t*)g,
                                     (__attribute__((address_space(3))) uint32_t*)l, 16, 0, 0);
}

// ================= MFMA-fragment-packed operand layout (R5-proven) ========
// Element (row, col) of a row-major [M][1024] bf16 matrix lives at ushort
// index  g*512 + lane*8 + e   where g = ((row>>4)*16 + kc)*2 + s,
// lane = q*16 + (row&15),  kc = col>>6, s = (col>>5)&1, q = (col>>3)&3,
// e = col&7.  A wave's fragment load is ONE coalesced global_load_dwordx4
// -- no LDS, no barriers.

__global__ void pack_w_kernel(const float* __restrict__ W,
                              ushort* __restrict__ whp, ushort* __restrict__ wlp) {
    int uid = blockIdx.x * 256 + threadIdx.x;   // 32768 units of 8 elems
    int l = uid & 63, s = (uid >> 6) & 1, kc = (uid >> 7) & 15, R = uid >> 11;
    int row = R * 16 + (l & 15);
    int col = kc * 64 + s * 32 + (l >> 4) * 8;
    const float* src = W + (size_t)row * V_DIM + col;
    ushort* dh = whp + (size_t)uid * 8;
    ushort* dl = wlp + (size_t)uid * 8;
#pragma unroll
    for (int e = 0; e < 8; ++e) {
        float w = src[e];
        ushort hi = bf16_rn(w);
        dh[e] = hi;
        dl[e] = bf16_rn(w - bf16_to_f32(hi));
    }
}

__global__ void pack_batch_kernel(const float* __restrict__ batch,
                                  ushort* __restrict__ bp) {
    int uid = blockIdx.x * 256 + threadIdx.x;   // 2,097,152 units
    int l = uid & 63, s = (uid >> 6) & 1, kc = (uid >> 7) & 15, R = uid >> 11;
    int row = R * 16 + (l & 15);
    int col = kc * 64 + s * 32 + (l >> 4) * 8;
    const float* src = batch + (size_t)row * V_DIM + col;
    ushort* d = bp + (size_t)uid * 8;
#pragma unroll
    for (int e = 0; e < 8; ++e) d[e] = bf16_rn(src[e]);
}

// ---------------- Barrier-free LDS-free GEMM block body (R5/R6-proven) --------
// C[64x64] tile of A[Mx1024] * W^T (hi+lo split) + bias. 4 waves, each 32x32.
// MFMA values and accumulation order bit-identical to round-0.
template <int MODE>
__device__ __forceinline__ void gemm_block_p(
    const int m0, const int n0,
    const ushort* __restrict__ Ap, const ushort* __restrict__ Bhp,
    const ushort* __restrict__ Blp, const float* __restrict__ bias,
    ushort* __restrict__ out, ushort* __restrict__ out2,
    const uint32_t key0, const uint32_t key1) {
    const int lane = threadIdx.x & 63;
    const int w = threadIdx.x >> 6;      // 0..3
    const int wm = (w & 1) * 32;
    const int wn = (w >> 1) * 32;
    const int q = lane >> 4;
    const int l15 = lane & 15;

    // R-group stride = 16 kc * 2 s * 512 = 16384 ushorts (32 KB)
    const ushort* apA = Ap + (size_t)((m0 >> 4) + (wm >> 4)) * 16384 + lane * 8;
    const ushort* apBh = Bhp + (size_t)((n0 >> 4) + (wn >> 4)) * 16384 + lane * 8;
    const ushort* apBl = Blp + (size_t)((n0 >> 4) + (wn >> 4)) * 16384 + lane * 8;

    f32x4 acc[2][2] = {};

#pragma unroll 2
    for (int kc = 0; kc < 16; ++kc) {
#pragma unroll
        for (int s = 0; s < 2; ++s) {
            const int go = kc * 1024 + s * 512;
            bf16x8 af[2], bh[2], bl[2];
#pragma unroll
            for (int i = 0; i < 2; ++i)
                af[i] = *(const bf16x8*)(apA + go + i * 16384);
#pragma unroll
            for (int j = 0; j < 2; ++j) {
                bh[j] = *(const bf16x8*)(apBh + go + j * 16384);
                bl[j] = *(const bf16x8*)(apBl + go + j * 16384);
            }
#pragma unroll
            for (int i = 0; i < 2; ++i)
#pragma unroll
                for (int j = 0; j < 2; ++j) {
                    acc[i][j] = __builtin_amdgcn_mfma_f32_16x16x32_bf16(af[i], bh[j], acc[i][j], 0, 0, 0);
                    acc[i][j] = __builtin_amdgcn_mfma_f32_16x16x32_bf16(af[i], bl[j], acc[i][j], 0, 0, 0);
                }
        }
    }

    const int orow = q * 4;
#pragma unroll
    for (int i = 0; i < 2; ++i) {
#pragma unroll
        for (int j = 0; j < 2; ++j) {
            int col = n0 + wn + j * 16 + l15;
            float bv = bias[col];
#pragma unroll
            for (int r = 0; r < 4; ++r) {
                int row = m0 + wm + i * 16 + orow + r;
                float val = acc[i][j][r] + bv;
                if (MODE == 0) {
                    float E = expf(-val);
                    uint32_t e = (uint32_t)row * (uint32_t)H_DIM + (uint32_t)col;
                    float u = tf_uniform(key0, key1, e);
                    out[(size_t)row * H_DIM + col] = (fmaf(u, E, u) < 1.0f) ? (ushort)0x3F80 : (ushort)0;
                } else if (MODE == 3) {
                    float E = expf(-val);
                    float sg = 1.0f / (1.0f + E);
                    uint32_t e = (uint32_t)row * (uint32_t)H_DIM + (uint32_t)col;
                    float u = tf_uniform(key0, key1, e);
                    out[(size_t)row * H_DIM + col] = (fmaf(u, E, u) < 1.0f) ? (ushort)0x3F80 : (ushort)0;
                    out2[(size_t)row * H_DIM + col] = bf16_rn(sg);
                } else {
                    float sg = 1.0f / (1.0f + expf(-val));
                    out[(size_t)row * H_DIM + col] = bf16_rn(sg);
                }
            }
        }
    }
}

// ---------------- Sparse v-side sampler body, 1 row per wave (R14) ----------
// Body identical to the R5/R6 refcheck'd packed-write version; only the
// row->wave assignment changes (4 rows/block, 1 per wave) so blocks are
// finer-grained and the grid (2048 vs-units) keeps CUs full through the tail.
__device__ __forceinline__ void vsample_row(
    const ushort* __restrict__ h, const float* __restrict__ W,
    const float* __restrict__ vb, ushort* __restrict__ vpack,
    ushort* __restrict__ vrow, int write_row,
    uint32_t key0, uint32_t key1, int b) {
    const int lane = threadIdx.x & 63;

    float vbr[16];
#pragma unroll
    for (int t = 0; t < 16; ++t) vbr[t] = vb[lane + 64 * t];

    ushort4 hv = ((const ushort4*)(h + (size_t)b * H_DIM))[lane];
    unsigned long long masks[4];
    masks[0] = __ballot(hv.x != 0);
    masks[1] = __ballot(hv.y != 0);
    masks[2] = __ballot(hv.z != 0);
    masks[3] = __ballot(hv.w != 0);

    float acc[16];
#pragma unroll
    for (int t = 0; t < 16; ++t) acc[t] = 0.0f;

#pragma unroll
    for (int s = 0; s < 4; ++s) {
        unsigned long long m = masks[s];
        while (m) {  // wave-uniform loop, no divergence
            int l = __ffsll(m) - 1;
            m &= m - 1;
            int j = l * 4 + s;
            const float* wrow = W + (size_t)j * V_DIM + lane;
#pragma unroll
            for (int t = 0; t < 16; ++t) acc[t] += wrow[64 * t];
        }
    }

    const uint32_t ebase = (uint32_t)b * (uint32_t)V_DIM + (uint32_t)lane;
    // packed destination for (b, col = lane + 64t):  kc = t
    ushort* vp = vpack + (size_t)(b >> 4) * 16384 + (b & 15) * 8 +
                 ((lane >> 5) & 1) * 512 + ((lane >> 3) & 3) * 128 + (lane & 7);
    ushort* orow = vrow + (size_t)b * V_DIM + lane;
#pragma unroll
    for (int t = 0; t < 16; ++t) {
        float pre = acc[t] + vbr[t];
        float E = expf(-pre);
        float u = tf_uniform(key0, key1, ebase + 64u * (uint32_t)t);
        ushort val = (fmaf(u, E, u) < 1.0f) ? (ushort)0x3F80 : (ushort)0;
        vp[t * 1024] = val;
        if (write_row) orow[64 * t] = val;
    }
}

// ---------------- Standalone half-batch GEMM (slots 0 and 17) ----------------
template <int MODE>
__global__ __launch_bounds__(256, 8) void gemm_only(
    const ushort* __restrict__ Ap, const ushort* __restrict__ Bhp,
    const ushort* __restrict__ Blp, const float* __restrict__ bias,
    ushort* __restrict__ out, ushort* __restrict__ out2,
    uint32_t key0, uint32_t key1, int mbase) {
    gemm_block_p<MODE>(mbase + blockIdx.x * 64, blockIdx.y * 64, Ap, Bhp, Blp,
                       bias, out, out2, key0, key1);
}

// ---------------- Hybrid dispatch: vsample(half X) || hgemm(half Y) ---------
// R14: zero LDS (packed gemm) + launch_bounds(256,8) -> 8 blocks/CU (vs 6),
// and vsample split to 4 rows/block (1/wave) -> 2560 total blocks (~10/CU) so
// CUs stay full through the tail. Pattern [vs x4, g] x 512.
template <int MODE>
__global__ __launch_bounds__(256, 8) void hybrid_step(
    const ushort* __restrict__ Ap, const ushort* __restrict__ Whp,
    const ushort* __restrict__ Wlp, const float* __restrict__ hb,
    ushort* __restrict__ hout, ushort* __restrict__ out2,
    uint32_t gk0, uint32_t gk1, int gemm_mbase,
    const ushort* __restrict__ hprev, const float* __restrict__ Wf,
    const float* __restrict__ vb, ushort* __restrict__ vpack,
    ushort* __restrict__ vrow, int write_row,
    uint32_t vk0, uint32_t vk1, int vs_base) {
    const int bid = blockIdx.x;           // 0..2559
    const int g5 = bid / 5;
    const int r5 = bid - g5 * 5;
    if (r5 < 4) {
        const int u = g5 * 4 + r5;        // 0..2047 vs-units (4 rows each)
        const int w = threadIdx.x >> 6;   // wave -> row
        vsample_row(hprev, Wf, vb, vpack, vrow, write_row, vk0, vk1,
                    vs_base + u * 4 + w);
    } else {
        const int g = g5;                 // 0..511
        const int gx = g & 127;           // 8192/64 = 128 m-blocks
        const int gy = g >> 7;            // 4 n-blocks
        gemm_block_p<MODE>(gemm_mbase + gx * 64, gy * 64, Ap, Whp, Wlp, hb,
                           hout, out2, gk0, gk1);
    }
}

// ---------------- gw split-K GEMM -> PARTIALS (R12-proven, no atomics) ------
__global__ __launch_bounds__(256, 4) void mfma_gemm_part(
    const ushort* __restrict__ A, const ushort* __restrict__ Bt,
    float* __restrict__ part, int N, int K, int k_slice) {
    __shared__ __align__(16) ushort As[64 * 64];
    __shared__ __align__(16) ushort Bs[64 * 64];

    const int tid = threadIdx.x;
    const int lane = tid & 63;
    const int w = tid >> 6;
    const int m0 = blockIdx.x * 64;
    const int n0 = blockIdx.y * 64;
    const int kbase = blockIdx.z * k_slice;

    const int wm = (w & 1) * 32;
    const int wn = (w >> 1) * 32;
    const int q = lane >> 4;
    const int l15 = lane & 15;

    const ushort* asrc[2];
    const ushort* bsrc[2];
#pragma unroll
    for (int i = 0; i < 2; ++i) {
        const int j = w * 2 + i;
        const int row = j * 8 + (lane >> 3);
        const int sl = (lane & 7) ^ (row & 7);
        const size_t off = (size_t)row * K + (sl >> 2) * 32 + (sl & 3) * 8;
        asrc[i] = A + (size_t)m0 * K + off;
        bsrc[i] = Bt + (size_t)n0 * K + off;
    }

    f32x4 acc[2][2] = {};

    for (int kt = 0; kt < k_slice; kt += 64) {
        const int k0 = kbase + kt;
#pragma unroll
        for (int i = 0; i < 2; ++i) {
            gload_lds16(asrc[i] + k0, &As[(w * 2 + i) * 512]);
            gload_lds16(bsrc[i] + k0, &Bs[(w * 2 + i) * 512]);
        }
        __syncthreads();
#pragma unroll
        for (int s = 0; s < 2; ++s) {
            bf16x8 af[2], bf[2];
#pragma unroll
            for (int i = 0; i < 2; ++i) {
                const int ra = wm + i * 16 + l15;
                const int rb = wn + i * 16 + l15;
                af[i] = *(const bf16x8*)((const char*)As + ra * 128 +
                                         (((s * 4 + q) ^ (ra & 7)) * 16));
                bf[i] = *(const bf16x8*)((const char*)Bs + rb * 128 +
                                         (((s * 4 + q) ^ (rb & 7)) * 16));
            }
#pragma unroll
            for (int i = 0; i < 2; ++i)
#pragma unroll
                for (int j = 0; j < 2; ++j)
                    acc[i][j] = __builtin_amdgcn_mfma_f32_16x16x32_bf16(af[i], bf[j], acc[i][j], 0, 0, 0);
        }
        __syncthreads();
    }

    float* pout = part + (size_t)blockIdx.z * (H_DIM * V_DIM);
    const int orow = q * 4;
#pragma unroll
    for (int i = 0; i < 2; ++i)
#pragma unroll
        for (int j = 0; j < 2; ++j) {
            int col = n0 + wn + j * 16 + l15;
#pragma unroll
            for (int r = 0; r < 4; ++r) {
                int row = m0 + wm + i * 16 + orow + r;
                pout[(size_t)row * N + col] = acc[i][j][r];   // plain store
            }
        }
}

// ---------------- owner-reduce: gw[idx] += sum_z partials[z][idx] ----------
__global__ __launch_bounds__(256) void reduce_gw(
    const float* __restrict__ part, float* __restrict__ gw, int nz) {
    const int idx = blockIdx.x * 256 + threadIdx.x;   // 0..262143
    float s = 0.0f;
    for (int z = 0; z < nz; ++z)
        s += part[(size_t)z * (H_DIM * V_DIM) + idx];
    gw[idx] += s;   // single owner per idx, no atomics
}

// ---------------- log-norm ----------------
__global__ __launch_bounds__(256) void lognorm_kernel(
    const ushort* __restrict__ phk, const ushort* __restrict__ vk,
    const float* __restrict__ vb, float* __restrict__ inv) {
    int b = blockIdx.x;
    int tid = threadIdx.x;
    float p = bf16_to_f32(phk[(size_t)b * H_DIM + tid]);
    float s = -log1pf(-p);
    for (int j = tid; j < V_DIM; j += 256)
        s += bf16_to_f32(vk[(size_t)b * V_DIM + j]) * vb[j];
    for (int off = 32; off > 0; off >>= 1) s += __shfl_down(s, off, 64);
    __shared__ float wsum[4];
    int lane = tid & 63, wid = tid >> 6;
    if (lane == 0) wsum[wid] = s;
    __syncthreads();
    if (tid == 0) {
        float t = wsum[0] + wsum[1] + wsum[2] + wsum[3];
        inv[b] = expf(-t) * (1.0f / 16384.0f);
    }
}

// ---------------- transposes for gw GEMM ----------------
__global__ void build_At(const ushort* __restrict__ P, const float* __restrict__ inv,
                         float sgn, ushort* __restrict__ At) {
    __shared__ float T[64][65];
    int c = threadIdx.x & 63;
    int rb = threadIdx.x >> 6;
    int b0 = blockIdx.x * 64;
    int h0 = blockIdx.y * 64;
    for (int r = rb; r < 64; r += 4) {
        int b = b0 + r;
        T[c][r] = sgn * inv[b] * bf16_to_f32(P[(size_t)b * H_DIM + h0 + c]);
    }
    __syncthreads();
    for (int r = rb; r < 64; r += 4)
        At[(size_t)(h0 + r) * B_DIM + b0 + c] = bf16_rn(T[r][c]);
}

__global__ void build_Bt(const ushort* __restrict__ Sb, const float* __restrict__ Sf,
                         int use_f32, ushort* __restrict__ Bt) {
    __shared__ ushort T[64][65];
    int c = threadIdx.x & 63;
    int rb = threadIdx.x >> 6;
    int b0 = blockIdx.x * 64;
    int v0 = blockIdx.y * 64;
    for (int r = rb; r < 64; r += 4) {
        int b = b0 + r;
        T[c][r] = use_f32 ? bf16_rn(Sf[(size_t)b * V_DIM + v0 + c])
                          : Sb[(size_t)b * V_DIM + v0 + c];
    }
    __syncthreads();
    for (int r = rb; r < 64; r += 4)
        Bt[(size_t)(v0 + r) * B_DIM + b0 + c] = T[r][c];
}

// ---------------- g_vb / g_hb ----------------
__global__ void gvb_kernel(const ushort* __restrict__ vk, const float* __restrict__ batchf,
                           const float* __restrict__ inv, float* __restrict__ gvb) {
    int col = blockIdx.x * 256 + threadIdx.x;
    int b0 = blockIdx.y * 128;
    float acc = 0.0f;
    for (int r = 0; r < 128; ++r) {
        int b = b0 + r;
        acc += inv[b] * (bf16_to_f32(vk[(size_t)b * V_DIM + col]) -
                         batchf[(size_t)b * V_DIM + col]);
    }
    atomicAdd(&gvb[col], acc);
}

__global__ void ghb_kernel(const ushort* __restrict__ phk, const ushort* __restrict__ ph0,
                           const float* __restrict__ inv, float* __restrict__ ghb) {
    int col = threadIdx.x;
    int b0 = blockIdx.x * 256;
    float acc = 0.0f;
    for (int r = 0; r < 256; ++r) {
        int b = b0 + r;
        acc += inv[b] * (bf16_to_f32(phk[(size_t)b * H_DIM + col]) -
                         bf16_to_f32(ph0[(size_t)b * H_DIM + col]));
    }
    atomicAdd(&ghb[col], acc);
}

extern "C" void kernel_launch(void* const* d_in, const int* in_sizes, int n_in,
                              void* d_out, int out_size, void* d_ws, size_t ws_size,
                              hipStream_t stream) {
    const float* batch = (const float*)d_in[0];
    const float* W = (const float*)d_in[1];
    const float* vb = (const float*)d_in[2];
    const float* hb = (const float*)d_in[3];

    char* base = (char*)d_ws;
    ushort* w_hi_p = (ushort*)(base + 0);           // 512 KB packed W hi
    ushort* w_lo_p = (ushort*)(base + 524288);      // 512 KB packed W lo
    float*  inv    = (float*)(base + 1048576);      // 64 KB
    ushort* v_pack = (ushort*)(base + 2097152);     // 32 MB (tail: Bt alias)
    ushort* Bt     = v_pack;
    ushort* v_row  = (ushort*)(base + 35651584);    // 32 MB (early: batch_p alias;
    ushort* batch_p = v_row;                        //  tail: part alias AFTER
    float*  part   = (float*)(base + 35651584);     //  build_Bt pos consumed v_row)
    ushort* h_cur  = (ushort*)(base + 69206016);    // 8 MB (tail: At alias)
    ushort* At     = h_cur;
    ushort* ph0b   = (ushort*)(base + 77594624);    // 8 MB
    ushort* phkb   = (ushort*)(base + 85983232);    // 8 MB -> total 94371840 B

    float* gw  = (float*)d_out;
    float* gvb = gw + (size_t)H_DIM * V_DIM;
    float* ghb = gvb + V_DIM;

    hipMemsetAsync(d_out, 0, (size_t)out_size * sizeof(float), stream);

    // Partitionable threefry split of key(42): subkey[n] = threefry((0,42),(0,n)).
    uint32_t sk0[16], sk1[16];
    for (int n = 0; n < 16; ++n) threefry2x32(0u, 42u, 0u, (uint32_t)n, &sk0[n], &sk1[n]);

    pack_w_kernel<<<dim3(128), dim3(256), 0, stream>>>(W, w_hi_p, w_lo_p);
    pack_batch_kernel<<<dim3(8192), dim3(256), 0, stream>>>(batch, batch_p);

    const int NB_VS = HALF_B / 4;          // 2048 vs-units per half (4 rows each)
    const int NB_G  = (HALF_B / 64) * 4;   // 512 gemm blocks per half
    const dim3 HYB(NB_VS + NB_G);          // 2560 = [vs x4, g] x 512

    // slot 0: gemm(half0, step0, MODE3)
    gemm_only<3><<<dim3(128, 4), dim3(256), 0, stream>>>(
        batch_p, w_hi_p, w_lo_p, hb, h_cur, ph0b, sk0[0], sk1[0], 0);

    for (int s = 0; s < K_STEPS; ++s) {
        const int wr = (s == K_STEPS - 1) ? 1 : 0;   // write v_row at last step
        // slot 2s+1: gemm(half1, step s) || vsample(half0, step s)
        if (s == 0) {
            hybrid_step<3><<<HYB, dim3(256), 0, stream>>>(
                batch_p, w_hi_p, w_lo_p, hb, h_cur, ph0b, sk0[0], sk1[0], HALF_B,
                h_cur, W, vb, v_pack, v_row, wr, sk0[1], sk1[1], 0);
        } else {
            hybrid_step<0><<<HYB, dim3(256), 0, stream>>>(
                v_pack, w_hi_p, w_lo_p, hb, h_cur, nullptr, sk0[2 * s], sk1[2 * s], HALF_B,
                h_cur, W, vb, v_pack, v_row, wr, sk0[2 * s + 1], sk1[2 * s + 1], 0);
        }
        // slot 2s+2: gemm(half0, step s+1 | final) || vsample(half1, step s)
        if (s < K_STEPS - 1) {
            hybrid_step<0><<<HYB, dim3(256), 0, stream>>>(
                v_pack, w_hi_p, w_lo_p, hb, h_cur, nullptr, sk0[2 * s + 2], sk1[2 * s + 2], 0,
                h_cur, W, vb, v_pack, v_row, wr, sk0[2 * s + 1], sk1[2 * s + 1], HALF_B);
        } else {
            hybrid_step<1><<<HYB, dim3(256), 0, stream>>>(
                v_pack, w_hi_p, w_lo_p, hb, phkb, nullptr, 0u, 0u, 0,
                h_cur, W, vb, v_pack, v_row, wr, sk0[2 * s + 1], sk1[2 * s + 1], HALF_B);
        }
    }
    // slot 17: gemm(half1, final phk, MODE1)
    gemm_only<1><<<dim3(128, 4), dim3(256), 0, stream>>>(
        v_pack, w_hi_p, w_lo_p, hb, phkb, nullptr, 0u, 0u, HALF_B);

    lognorm_kernel<<<dim3(B_DIM), dim3(256), 0, stream>>>(phkb, v_row, vb, inv);
    ghb_kernel<<<dim3(B_DIM / 256), dim3(256), 0, stream>>>(phkb, ph0b, inv, ghb);
    gvb_kernel<<<dim3(V_DIM / 256, B_DIM / 128), dim3(256), 0, stream>>>(v_row, batch, inv, gvb);

    // g_W positive phase: build -> split-K partials -> owner-reduce (no atomics).
    // part overwrites the v_row region AFTER build_Bt pos consumed it.
    build_At<<<dim3(B_DIM / 64, H_DIM / 64), dim3(256), 0, stream>>>(phkb, inv, 1.0f, At);
    build_Bt<<<dim3(B_DIM / 64, V_DIM / 64), dim3(256), 0, stream>>>(v_row, nullptr, 0, Bt);
    mfma_gemm_part<<<dim3(H_DIM / 64, V_DIM / 64, 16), dim3(256), 0, stream>>>(
        At, Bt, part, V_DIM, B_DIM, 1024);
    reduce_gw<<<dim3(H_DIM * V_DIM / 256), dim3(256), 0, stream>>>(part, gw, 16);
    // g_W negative phase
    build_At<<<dim3(B_DIM / 64, H_DIM / 64), dim3(256), 0, stream>>>(ph0b, inv, -1.0f, At);
    build_Bt<<<dim3(B_DIM / 64, V_DIM / 64), dim3(256), 0, stream>>>(nullptr, batch, 1, Bt);
    mfma_gemm_part<<<dim3(H_DIM / 64, V_DIM / 64, 16), dim3(256), 0, stream>>>(
        At, Bt, part, V_DIM, B_DIM, 1024);
    reduce_gw<<<dim3(H_DIM * V_DIM / 256), dim3(256), 0, stream>>>(part, gw, 16);
}

// Round 15
// 837.729 us; speedup vs baseline: 1.2395x; 1.2395x over previous
//
#include <hip/hip_runtime.h>
#include <stdint.h>

#define B_DIM 16384
#define V_DIM 1024
#define H_DIM 256
#define K_STEPS 8
#define HALF_B 8192

typedef short bf16x8 __attribute__((ext_vector_type(8)));
typedef float f32x4 __attribute__((ext_vector_type(4)));

// ---------------- Threefry-2x32-20, bit-exact JAX replica ----------------
__host__ __device__ inline uint32_t rotl32(uint32_t v, int r) {
#if defined(__HIP_DEVICE_COMPILE__)
    return __builtin_amdgcn_alignbit(v, v, (uint32_t)(32 - r));
#else
    return (v << r) | (v >> (32 - r));
#endif
}

__host__ __device__ inline void threefry2x32(uint32_t k0, uint32_t k1,
                                             uint32_t x0, uint32_t x1,
                                             uint32_t* o0, uint32_t* o1) {
    uint32_t k2 = k0 ^ k1 ^ 0x1BD11BDAu;
    x0 += k0; x1 += k1;
#define TF_RND(r) { x0 += x1; x1 = rotl32(x1, (r)); x1 ^= x0; }
    TF_RND(13) TF_RND(15) TF_RND(26) TF_RND(6)
    x0 += k1; x1 += k2 + 1u;
    TF_RND(17) TF_RND(29) TF_RND(16) TF_RND(24)
    x0 += k2; x1 += k0 + 2u;
    TF_RND(13) TF_RND(15) TF_RND(26) TF_RND(6)
    x0 += k0; x1 += k1 + 3u;
    TF_RND(17) TF_RND(29) TF_RND(16) TF_RND(24)
    x0 += k1; x1 += k2 + 4u;
    TF_RND(13) TF_RND(15) TF_RND(26) TF_RND(6)
    x0 += k2; x1 += k0 + 5u;
#undef TF_RND
    *o0 = x0; *o1 = x1;
}

// Partitionable-threefry uniform (bits = o0 ^ o1 of counter (0, e)).
__device__ inline float tf_uniform(uint32_t key0, uint32_t key1, uint32_t e) {
    uint32_t o0, o1;
    threefry2x32(key0, key1, 0u, e, &o0, &o1);
    uint32_t bits = o0 ^ o1;
    return __uint_as_float((bits >> 9) | 0x3f800000u) - 1.0f;
}

__device__ inline uint16_t bf16_rn(float f) {
    uint32_t u = __float_as_uint(f);
    uint32_t r = u + 0x7FFFu + ((u >> 16) & 1u);
    return (uint16_t)(r >> 16);
}
__device__ inline float bf16_to_f32(uint16_t h) {
    return __uint_as_float(((uint32_t)h) << 16);
}

__device__ inline void gload_lds16(const void* g, void* l) {
    __builtin_amdgcn_global_load_lds((const __attribute__((address_space(1))) uint32_t*)g,
                                     (__attribute__((address_space(3))) uint32_t*)l, 16, 0, 0);
}

// ---------------- GEMM block body (R0 math, XOR-swizzled merged LDS tiles) --------
// C[64 x 64] tile of A[M x K] * Bt[N x K]^T (+bias). 4 waves, each 32x32 (2x2 frags).
// LDS: Am [64 rows][128 B] slots {s b2, q b1:0} ^ (row&7)        (8 KB)
//      Bm [64 rows][256 B] slots {s b3, hl b2, q b1:0} ^ (row&15) (16 KB)
// Staging keeps LINEAR gload_lds destinations; the per-lane GLOBAL source is
// pre-swizzled (rule #21 both-sides). Frag reads land 2 lanes/bank-group = free.
// MFMA inputs and accumulation order are bit-identical to the round-0 kernel.
template <int MODE>
__device__ __forceinline__ void gemm_block(
    const int m0, const int n0,
    const ushort* __restrict__ A, const ushort* __restrict__ Bhi,
    const ushort* __restrict__ Blo, const float* __restrict__ bias,
    ushort* __restrict__ out, ushort* __restrict__ out2,
    const int N, const int K, const uint32_t key0, const uint32_t key1,
    ushort* Am, ushort* Bm) {
    const int tid = threadIdx.x;
    const int lane = tid & 63;
    const int w = tid >> 6;            // 0..3
    const int wm = (w & 1) * 32;
    const int wn = (w >> 1) * 32;
    const int q = lane >> 4;
    const int l15 = lane & 15;

    // staging sources (k0-invariant). A: issue j=w*2+i covers rows j*8..+7.
    const ushort* asrc[2];
#pragma unroll
    for (int i = 0; i < 2; ++i) {
        const int j = w * 2 + i;
        const int row = j * 8 + (lane >> 3);
        const int sl = (lane & 7) ^ (row & 7);
        asrc[i] = A + (size_t)(m0 + row) * K + (sl >> 2) * 32 + (sl & 3) * 8;
    }
    // B: issue j=w*4+i covers rows j*4..+3 (hi+lo merged per row).
    const ushort* bsrc[4];
#pragma unroll
    for (int i = 0; i < 4; ++i) {
        const int j = w * 4 + i;
        const int row = j * 4 + (lane >> 4);
        const int sl = (lane & 15) ^ (row & 15);
        const int hl = (sl >> 2) & 1;
        bsrc[i] = (hl ? Blo : Bhi) + (size_t)(n0 + row) * K + (sl >> 3) * 32 + (sl & 3) * 8;
    }

    f32x4 acc[2][2] = {};

    for (int k0 = 0; k0 < K; k0 += 64) {
#pragma unroll
        for (int i = 0; i < 2; ++i)
            gload_lds16(asrc[i] + k0, &Am[(w * 2 + i) * 512]);
#pragma unroll
        for (int i = 0; i < 4; ++i)
            gload_lds16(bsrc[i] + k0, &Bm[(w * 4 + i) * 512]);
        __syncthreads();
#pragma unroll
        for (int s = 0; s < 2; ++s) {
            bf16x8 af[2], bh[2], bl[2];
#pragma unroll
            for (int i = 0; i < 2; ++i) {
                const int ra = wm + i * 16 + l15;
                af[i] = *(const bf16x8*)((const char*)Am + ra * 128 +
                                         (((s * 4 + q) ^ (ra & 7)) * 16));
            }
#pragma unroll
            for (int j = 0; j < 2; ++j) {
                const int rb = wn + j * 16 + l15;
                const char* bb = (const char*)Bm + rb * 256;
                bh[j] = *(const bf16x8*)(bb + (((s * 8 + q) ^ (rb & 15)) * 16));
                bl[j] = *(const bf16x8*)(bb + (((s * 8 + 4 + q) ^ (rb & 15)) * 16));
            }
#pragma unroll
            for (int i = 0; i < 2; ++i)
#pragma unroll
                for (int j = 0; j < 2; ++j) {
                    acc[i][j] = __builtin_amdgcn_mfma_f32_16x16x32_bf16(af[i], bh[j], acc[i][j], 0, 0, 0);
                    acc[i][j] = __builtin_amdgcn_mfma_f32_16x16x32_bf16(af[i], bl[j], acc[i][j], 0, 0, 0);
                }
        }
        __syncthreads();
    }

    const int orow = q * 4;
#pragma unroll
    for (int i = 0; i < 2; ++i) {
#pragma unroll
        for (int j = 0; j < 2; ++j) {
            int col = n0 + wn + j * 16 + l15;
            float bv = bias[col];
#pragma unroll
            for (int r = 0; r < 4; ++r) {
                int row = m0 + wm + i * 16 + orow + r;
                float val = acc[i][j][r] + bv;
                if (MODE == 0) {
                    float E = expf(-val);
                    uint32_t e = (uint32_t)row * (uint32_t)N + (uint32_t)col;
                    float u = tf_uniform(key0, key1, e);
                    out[(size_t)row * N + col] = (fmaf(u, E, u) < 1.0f) ? (ushort)0x3F80 : (ushort)0;
                } else if (MODE == 3) {
                    float E = expf(-val);
                    float sg = 1.0f / (1.0f + E);
                    uint32_t e = (uint32_t)row * (uint32_t)N + (uint32_t)col;
                    float u = tf_uniform(key0, key1, e);
                    out[(size_t)row * N + col] = (fmaf(u, E, u) < 1.0f) ? (ushort)0x3F80 : (ushort)0;
                    out2[(size_t)row * N + col] = bf16_rn(sg);
                } else {
                    float sg = 1.0f / (1.0f + expf(-val));
                    out[(size_t)row * N + col] = bf16_rn(sg);
                }
            }
        }
    }
}

// ---------------- Sparse v-side sampler body (round-0 proven, fma-compare) -------
__device__ __forceinline__ void vsample_block(
    const ushort* __restrict__ h, const float* __restrict__ W,
    const float* __restrict__ vb, ushort* __restrict__ vout,
    uint32_t key0, uint32_t key1, int row_base) {
    const int lane = threadIdx.x & 63;
    const int wid = threadIdx.x >> 6;

    float vbr[16];
#pragma unroll
    for (int t = 0; t < 16; ++t) vbr[t] = vb[lane + 64 * t];

    const int rb2 = row_base + wid * 2;
#pragma unroll
    for (int rr = 0; rr < 2; ++rr) {
        const int b = rb2 + rr;
        ushort4 hv = ((const ushort4*)(h + (size_t)b * H_DIM))[lane];
        unsigned long long masks[4];
        masks[0] = __ballot(hv.x != 0);
        masks[1] = __ballot(hv.y != 0);
        masks[2] = __ballot(hv.z != 0);
        masks[3] = __ballot(hv.w != 0);

        float acc[16];
#pragma unroll
        for (int t = 0; t < 16; ++t) acc[t] = 0.0f;

#pragma unroll
        for (int s = 0; s < 4; ++s) {
            unsigned long long m = masks[s];
            while (m) {  // wave-uniform loop, no divergence
                int l = __ffsll(m) - 1;
                m &= m - 1;
                int j = l * 4 + s;
                const float* wrow = W + (size_t)j * V_DIM + lane;
#pragma unroll
                for (int t = 0; t < 16; ++t) acc[t] += wrow[64 * t];
            }
        }

        const uint32_t ebase = (uint32_t)b * (uint32_t)V_DIM + (uint32_t)lane;
        ushort* orow = vout + (size_t)b * V_DIM + lane;
#pragma unroll
        for (int t = 0; t < 16; ++t) {
            float pre = acc[t] + vbr[t];
            float E = expf(-pre);
            float u = tf_uniform(key0, key1, ebase + 64u * (uint32_t)t);
            orow[64 * t] = (fmaf(u, E, u) < 1.0f) ? (ushort)0x3F80 : (ushort)0;
        }
    }
}

// ---------------- Standalone half-batch GEMM (slots 0 and 17) ----------------
template <int MODE>
__global__ __launch_bounds__(256, 4) void gemm_only(
    const ushort* __restrict__ A, const ushort* __restrict__ Bhi,
    const ushort* __restrict__ Blo, const float* __restrict__ bias,
    ushort* __restrict__ out, ushort* __restrict__ out2,
    uint32_t key0, uint32_t key1, int mbase) {
    __shared__ __align__(16) ushort Am[64 * 64];
    __shared__ __align__(16) ushort Bm[64 * 128];
    gemm_block<MODE>(mbase + blockIdx.x * 64, blockIdx.y * 64, A, Bhi, Blo, bias,
                     out, out2, H_DIM, V_DIM, key0, key1, Am, Bm);
}

// ---------------- Hybrid dispatch: vsample(half X, step s') || hgemm(half Y, s) ---
// R4-proven (859 us): vsample blocks first, then gemm blocks.
template <int MODE>
__global__ __launch_bounds__(256, 4) void hybrid_step(
    const ushort* __restrict__ vin, const ushort* __restrict__ Whi,
    const ushort* __restrict__ Wlo, const float* __restrict__ hb,
    ushort* __restrict__ hout, ushort* __restrict__ out2,
    uint32_t gk0, uint32_t gk1, int gemm_mbase,
    const ushort* __restrict__ hprev, const float* __restrict__ Wf,
    const float* __restrict__ vb, ushort* __restrict__ vout,
    uint32_t vk0, uint32_t vk1, int vs_base, int nb_vs) {
    __shared__ __align__(16) ushort Am[64 * 64];
    __shared__ __align__(16) ushort Bm[64 * 128];
    const int bid = blockIdx.x;
    if (bid < nb_vs) {
        vsample_block(hprev, Wf, vb, vout, vk0, vk1, vs_base + bid * 8);
    } else {
        const int g = bid - nb_vs;
        const int gx = g & 127;        // 8192/64 = 128 m-blocks
        const int gy = g >> 7;         // 4 n-blocks
        gemm_block<MODE>(gemm_mbase + gx * 64, gy * 64, vin, Whi, Wlo, hb,
                         hout, out2, H_DIM, V_DIM, gk0, gk1, Am, Bm);
    }
}

// ---------------- gw split-K GEMM -> PARTIALS (R4 acc structure, no atomics) ------
// Identical staging/swizzle/MFMA to R4's proven 43us mfma_gemm_acc; only the
// epilogue changes: plain coalesced stores into part[z][256][1024] instead of
// 4.2M fp32 atomicAdds (R10 counters proved waves park on atomic completion:
// VALU 3.6%, Mfma 6%, occ 16%, nothing busy). Owner-reduce sums the partials.
__global__ __launch_bounds__(256, 4) void mfma_gemm_part(
    const ushort* __restrict__ A, const ushort* __restrict__ Bt,
    float* __restrict__ part, int N, int K, int k_slice) {
    __shared__ __align__(16) ushort As[64 * 64];   // [64 rows][128 B], A-scheme swizzle
    __shared__ __align__(16) ushort Bs[64 * 64];

    const int tid = threadIdx.x;
    const int lane = tid & 63;
    const int w = tid >> 6;
    const int m0 = blockIdx.x * 64;
    const int n0 = blockIdx.y * 64;
    const int kbase = blockIdx.z * k_slice;

    const int wm = (w & 1) * 32;
    const int wn = (w >> 1) * 32;
    const int q = lane >> 4;
    const int l15 = lane & 15;

    const ushort* asrc[2];
    const ushort* bsrc[2];
#pragma unroll
    for (int i = 0; i < 2; ++i) {
        const int j = w * 2 + i;
        const int row = j * 8 + (lane >> 3);
        const int sl = (lane & 7) ^ (row & 7);
        const size_t off = (size_t)row * K + (sl >> 2) * 32 + (sl & 3) * 8;
        asrc[i] = A + (size_t)m0 * K + off;
        bsrc[i] = Bt + (size_t)n0 * K + off;
    }

    f32x4 acc[2][2] = {};

    for (int kt = 0; kt < k_slice; kt += 64) {
        const int k0 = kbase + kt;
#pragma unroll
        for (int i = 0; i < 2; ++i) {
            gload_lds16(asrc[i] + k0, &As[(w * 2 + i) * 512]);
            gload_lds16(bsrc[i] + k0, &Bs[(w * 2 + i) * 512]);
        }
        __syncthreads();
#pragma unroll
        for (int s = 0; s < 2; ++s) {
            bf16x8 af[2], bf[2];
#pragma unroll
            for (int i = 0; i < 2; ++i) {
                const int ra = wm + i * 16 + l15;
                const int rb = wn + i * 16 + l15;
                af[i] = *(const bf16x8*)((const char*)As + ra * 128 +
                                         (((s * 4 + q) ^ (ra & 7)) * 16));
                bf[i] = *(const bf16x8*)((const char*)Bs + rb * 128 +
                                         (((s * 4 + q) ^ (rb & 7)) * 16));
            }
#pragma unroll
            for (int i = 0; i < 2; ++i)
#pragma unroll
                for (int j = 0; j < 2; ++j)
                    acc[i][j] = __builtin_amdgcn_mfma_f32_16x16x32_bf16(af[i], bf[j], acc[i][j], 0, 0, 0);
        }
        __syncthreads();
    }

    float* pout = part + (size_t)blockIdx.z * (H_DIM * V_DIM);
    const int orow = q * 4;
#pragma unroll
    for (int i = 0; i < 2; ++i)
#pragma unroll
        for (int j = 0; j < 2; ++j) {
            int col = n0 + wn + j * 16 + l15;
#pragma unroll
            for (int r = 0; r < 4; ++r) {
                int row = m0 + wm + i * 16 + orow + r;
                pout[(size_t)row * N + col] = acc[i][j][r];   // plain store
            }
        }
}

// ---------------- owner-reduce: gw[idx] += sum_z partials[z][idx] ----------
__global__ __launch_bounds__(256) void reduce_gw(
    const float* __restrict__ part, float* __restrict__ gw, int nz) {
    const int idx = blockIdx.x * 256 + threadIdx.x;   // 0..262143
    float s = 0.0f;
    for (int z = 0; z < nz; ++z)
        s += part[(size_t)z * (H_DIM * V_DIM) + idx];
    gw[idx] += s;   // single owner per idx, no atomics
}

// ---------------- W split into bf16 hi/lo ----------------
__global__ void wsplit_kernel(const float* __restrict__ W, ushort* __restrict__ whi,
                              ushort* __restrict__ wlo) {
    int idx = blockIdx.x * 256 + threadIdx.x;
    float w = W[idx];
    ushort hi = bf16_rn(w);
    float fhi = bf16_to_f32(hi);
    ushort lo = bf16_rn(w - fhi);
    whi[idx] = hi; wlo[idx] = lo;
}

__global__ void tobf16_kernel(const float* __restrict__ src, ushort* __restrict__ dst) {
    int idx = blockIdx.x * 256 + threadIdx.x;
    float4 f = ((const float4*)src)[idx];
    ushort4 o;
    o.x = bf16_rn(f.x); o.y = bf16_rn(f.y); o.z = bf16_rn(f.z); o.w = bf16_rn(f.w);
    ((ushort4*)dst)[idx] = o;
}

// ---------------- log-norm ----------------
__global__ __launch_bounds__(256) void lognorm_kernel(
    const ushort* __restrict__ phk, const ushort* __restrict__ vk,
    const float* __restrict__ vb, float* __restrict__ inv) {
    int b = blockIdx.x;
    int tid = threadIdx.x;
    float p = bf16_to_f32(phk[(size_t)b * H_DIM + tid]);
    float s = -log1pf(-p);
    for (int j = tid; j < V_DIM; j += 256)
        s += bf16_to_f32(vk[(size_t)b * V_DIM + j]) * vb[j];
    for (int off = 32; off > 0; off >>= 1) s += __shfl_down(s, off, 64);
    __shared__ float wsum[4];
    int lane = tid & 63, wid = tid >> 6;
    if (lane == 0) wsum[wid] = s;
    __syncthreads();
    if (tid == 0) {
        float t = wsum[0] + wsum[1] + wsum[2] + wsum[3];
        inv[b] = expf(-t) * (1.0f / 16384.0f);
    }
}

// ---------------- transposes for gw GEMM ----------------
__global__ void build_At(const ushort* __restrict__ P, const float* __restrict__ inv,
                         float sgn, ushort* __restrict__ At) {
    __shared__ float T[64][65];
    int c = threadIdx.x & 63;
    int rb = threadIdx.x >> 6;
    int b0 = blockIdx.x * 64;
    int h0 = blockIdx.y * 64;
    for (int r = rb; r < 64; r += 4) {
        int b = b0 + r;
        T[c][r] = sgn * inv[b] * bf16_to_f32(P[(size_t)b * H_DIM + h0 + c]);
    }
    __syncthreads();
    for (int r = rb; r < 64; r += 4)
        At[(size_t)(h0 + r) * B_DIM + b0 + c] = bf16_rn(T[r][c]);
}

__global__ void build_Bt(const ushort* __restrict__ Sb, const float* __restrict__ Sf,
                         int use_f32, ushort* __restrict__ Bt) {
    __shared__ ushort T[64][65];
    int c = threadIdx.x & 63;
    int rb = threadIdx.x >> 6;
    int b0 = blockIdx.x * 64;
    int v0 = blockIdx.y * 64;
    for (int r = rb; r < 64; r += 4) {
        int b = b0 + r;
        T[c][r] = use_f32 ? bf16_rn(Sf[(size_t)b * V_DIM + v0 + c])
                          : Sb[(size_t)b * V_DIM + v0 + c];
    }
    __syncthreads();
    for (int r = rb; r < 64; r += 4)
        Bt[(size_t)(v0 + r) * B_DIM + b0 + c] = T[r][c];
}

// ---------------- g_vb / g_hb ----------------
// gvb: 512 blocks (old (4,32) grid = 128 blocks left half the GPU idle).
__global__ void gvb_kernel(const ushort* __restrict__ vk, const ushort* __restrict__ vbat,
                           const float* __restrict__ inv, float* __restrict__ gvb) {
    int col = blockIdx.x * 256 + threadIdx.x;
    int b0 = blockIdx.y * 128;
    float acc = 0.0f;
    for (int r = 0; r < 128; ++r) {
        int b = b0 + r;
        acc += inv[b] * (bf16_to_f32(vk[(size_t)b * V_DIM + col]) -
                         bf16_to_f32(vbat[(size_t)b * V_DIM + col]));
    }
    atomicAdd(&gvb[col], acc);
}

__global__ void ghb_kernel(const ushort* __restrict__ phk, const ushort* __restrict__ ph0,
                           const float* __restrict__ inv, float* __restrict__ ghb) {
    int col = threadIdx.x;
    int b0 = blockIdx.x * 256;
    float acc = 0.0f;
    for (int r = 0; r < 256; ++r) {
        int b = b0 + r;
        acc += inv[b] * (bf16_to_f32(phk[(size_t)b * H_DIM + col]) -
                         bf16_to_f32(ph0[(size_t)b * H_DIM + col]));
    }
    atomicAdd(&ghb[col], acc);
}

extern "C" void kernel_launch(void* const* d_in, const int* in_sizes, int n_in,
                              void* d_out, int out_size, void* d_ws, size_t ws_size,
                              hipStream_t stream) {
    const float* batch = (const float*)d_in[0];
    const float* W = (const float*)d_in[1];
    const float* vb = (const float*)d_in[2];
    const float* hb = (const float*)d_in[3];

    char* base = (char*)d_ws;
    ushort* w_hi  = (ushort*)(base + 0);          // 512 KB
    ushort* w_lo  = (ushort*)(base + 524288);
    ushort* v_cur = (ushort*)(base + 2097152);    // 32 MB (tail: partials alias
    float*  part  = (float*)(base + 2097152);     //   AFTER build_Bt pos reads v_cur)
    float*  inv   = (float*)(base + 35651584);    // 64 KB
    ushort* h_cur = (ushort*)(base + 35717120);   // 8 MB (aliased: At after chain)
    ushort* At    = h_cur;
    ushort* batch_bf = (ushort*)(base + 44105728); // 32 MB (aliased: Bt after last use)
    ushort* Bt    = batch_bf;
    ushort* ph0b  = (ushort*)(base + 77660160);   // 8 MB
    ushort* phkb  = (ushort*)(base + 86048768);   // 8 MB -> total 94437376 B

    float* gw  = (float*)d_out;
    float* gvb = gw + (size_t)H_DIM * V_DIM;
    float* ghb = gvb + V_DIM;

    hipMemsetAsync(d_out, 0, (size_t)out_size * sizeof(float), stream);

    // Partitionable threefry split of key(42): subkey[n] = threefry((0,42),(0,n)).
    uint32_t sk0[16], sk1[16];
    for (int n = 0; n < 16; ++n) threefry2x32(0u, 42u, 0u, (uint32_t)n, &sk0[n], &sk1[n]);

    wsplit_kernel<<<dim3(1024), dim3(256), 0, stream>>>(W, w_hi, w_lo);
    tobf16_kernel<<<dim3(B_DIM * V_DIM / 4 / 256), dim3(256), 0, stream>>>(batch, batch_bf);

    const int NB_VS = HALF_B / 8;          // 1024 vsample blocks per half
    const int NB_G  = (HALF_B / 64) * 4;   // 512 gemm blocks per half
    const dim3 HYB(NB_VS + NB_G);

    // slot 0: gemm(half0, step0, MODE3)
    gemm_only<3><<<dim3(128, 4), dim3(256), 0, stream>>>(
        batch_bf, w_hi, w_lo, hb, h_cur, ph0b, sk0[0], sk1[0], 0);

    for (int s = 0; s < K_STEPS; ++s) {
        const ushort* vin = (s == 0) ? batch_bf : v_cur;
        // slot 2s+1: gemm(half1, step s) || vsample(half0, step s)
        if (s == 0) {
            hybrid_step<3><<<HYB, dim3(256), 0, stream>>>(
                vin, w_hi, w_lo, hb, h_cur, ph0b, sk0[0], sk1[0], HALF_B,
                h_cur, W, vb, v_cur, sk0[1], sk1[1], 0, NB_VS);
        } else {
            hybrid_step<0><<<HYB, dim3(256), 0, stream>>>(
                vin, w_hi, w_lo, hb, h_cur, nullptr, sk0[2 * s], sk1[2 * s], HALF_B,
                h_cur, W, vb, v_cur, sk0[2 * s + 1], sk1[2 * s + 1], 0, NB_VS);
        }
        // slot 2s+2: gemm(half0, step s+1 | final) || vsample(half1, step s)
        if (s < K_STEPS - 1) {
            hybrid_step<0><<<HYB, dim3(256), 0, stream>>>(
                v_cur, w_hi, w_lo, hb, h_cur, nullptr, sk0[2 * s + 2], sk1[2 * s + 2], 0,
                h_cur, W, vb, v_cur, sk0[2 * s + 1], sk1[2 * s + 1], HALF_B, NB_VS);
        } else {
            hybrid_step<1><<<HYB, dim3(256), 0, stream>>>(
                v_cur, w_hi, w_lo, hb, phkb, nullptr, 0u, 0u, 0,
                h_cur, W, vb, v_cur, sk0[2 * s + 1], sk1[2 * s + 1], HALF_B, NB_VS);
        }
    }
    // slot 17: gemm(half1, final phk, MODE1)
    gemm_only<1><<<dim3(128, 4), dim3(256), 0, stream>>>(
        v_cur, w_hi, w_lo, hb, phkb, nullptr, 0u, 0u, HALF_B);

    lognorm_kernel<<<dim3(B_DIM), dim3(256), 0, stream>>>(phkb, v_cur, vb, inv);
    ghb_kernel<<<dim3(B_DIM / 256), dim3(256), 0, stream>>>(phkb, ph0b, inv, ghb);
    gvb_kernel<<<dim3(V_DIM / 256, B_DIM / 128), dim3(256), 0, stream>>>(v_cur, batch_bf, inv, gvb);

    // g_W positive phase: build -> split-K partials (grid (4,16,16), k_slice
    // 1024; part overwrites v_cur region AFTER build_Bt pos consumed it) -> reduce.
    build_At<<<dim3(B_DIM / 64, H_DIM / 64), dim3(256), 0, stream>>>(phkb, inv, 1.0f, At);
    build_Bt<<<dim3(B_DIM / 64, V_DIM / 64), dim3(256), 0, stream>>>(v_cur, nullptr, 0, Bt);
    mfma_gemm_part<<<dim3(H_DIM / 64, V_DIM / 64, 16), dim3(256), 0, stream>>>(
        At, Bt, part, V_DIM, B_DIM, 1024);
    reduce_gw<<<dim3(H_DIM * V_DIM / 256), dim3(256), 0, stream>>>(part, gw, 16);
    // g_W negative phase
    build_At<<<dim3(B_DIM / 64, H_DIM / 64), dim3(256), 0, stream>>>(ph0b, inv, -1.0f, At);
    build_Bt<<<dim3(B_DIM / 64, V_DIM / 64), dim3(256), 0, stream>>>(nullptr, batch, 1, Bt);
    mfma_gemm_part<<<dim3(H_DIM / 64, V_DIM / 64, 16), dim3(256), 0, stream>>>(
        At, Bt, part, V_DIM, B_DIM, 1024);
    reduce_gw<<<dim3(H_DIM * V_DIM / 256), dim3(256), 0, stream>>>(part, gw, 16);
}